// Round 1
// baseline (372.689 us; speedup 1.0000x reference)
//
#include <hip/hip_runtime.h>
#include <cstdint>
#include <cstddef>

#define BATCH 8192
#define KC 8
#define NC 1024
#define DC 256
#define TAU 1e-3f

typedef __attribute__((ext_vector_type(8))) _Float16 half8;
typedef __attribute__((ext_vector_type(4))) _Float16 half4;
typedef __attribute__((ext_vector_type(4))) float floatx4;

__device__ __forceinline__ void async_load16(const void* g, void* l) {
    __builtin_amdgcn_global_load_lds((const __attribute__((address_space(1))) uint32_t*)g,
                                     (__attribute__((address_space(3))) uint32_t*)l, 16, 0, 0);
}

// XOR-swizzled LDS tile (128 rows x 64 halfs): row r, 16B chunk c at slot c^(r&7)
__device__ __forceinline__ int lidx(int r, int c) {
    return (r >> 3) * 1024 + (r & 7) * 128 + ((c ^ (r & 7)) * 16);
}
__device__ __forceinline__ half8 ldsr(const char* base, int r, int c) {
    return *(const half8*)(base + lidx(r, c));
}

// ---------------------------------------------------------------------------
// P: entries -> Ecat f16 [row][512] = [eh(256) | el(256)]; eef = fp32(|e|^2 via fp64)
// ---------------------------------------------------------------------------
__global__ __launch_bounds__(256) void prep_e_kernel(const float* __restrict__ entries,
                                                     _Float16* __restrict__ Ecat,
                                                     float* __restrict__ eef) {
    int wave = threadIdx.x >> 6, lane = threadIdx.x & 63;
    int row = blockIdx.x * 4 + wave;            // [0, 8192) = k*NC + n
    float4 v = ((const float4*)(entries + (size_t)row * DC))[lane];
    half4 h, l;
    h.x = (_Float16)v.x; h.y = (_Float16)v.y; h.z = (_Float16)v.z; h.w = (_Float16)v.w;
    l.x = (_Float16)(v.x - (float)h.x); l.y = (_Float16)(v.y - (float)h.y);
    l.z = (_Float16)(v.z - (float)h.z); l.w = (_Float16)(v.w - (float)h.w);
    _Float16* rp = Ecat + (size_t)row * 512;
    *(half4*)(rp + lane * 4)       = h;
    *(half4*)(rp + 256 + lane * 4) = l;
    double s = (double)v.x * v.x + (double)v.y * v.y + (double)v.z * v.z + (double)v.w * v.w;
    #pragma unroll
    for (int off = 32; off > 0; off >>= 1) s += __shfl_down(s, off, 64);
    if (lane == 0) eef[row] = (float)s;
}

// ---------------------------------------------------------------------------
// GEMM: grid 512 (k = blk&7 -> XCD-pinned, bt = blk>>3). 4 waves x 32 rows.
// A (x tile) full-K in registers as split-f16; B double-buffered via
// global_load_lds; 3 passes (xh*eh + xl*eh + xh*el) with bh reuse.
// Fused epilogue: per-row top-2 via plain f32 (ties -> flagged -> refine),
// out_q gather + exact fp64 loss.
// ---------------------------------------------------------------------------
__global__ __launch_bounds__(256, 2) void vq_gemm(const float* __restrict__ x,
                                                  const float* __restrict__ entries,
                                                  const _Float16* __restrict__ Ecat,
                                                  const float* __restrict__ eef,
                                                  float* __restrict__ out_idx,
                                                  float* __restrict__ out_q,
                                                  double* __restrict__ partial,
                                                  int* __restrict__ flag_list,
                                                  int* __restrict__ flag_cnt) {
    __shared__ alignas(16) char Bh[2][16384];
    __shared__ alignas(16) char Bl[2][16384];
    __shared__ float eef_lds[NC];
    __shared__ float tv1[128];
    __shared__ float tv2[128];
    __shared__ int   ti1[128];
    __shared__ int idx_lds[128];
    __shared__ double red[256];

    const int t = threadIdx.x;
    const int k  = blockIdx.x & 7;
    const int b0 = (blockIdx.x >> 3) * 128;
    const int w = t >> 6, lane = t & 63;
    const int quad = lane >> 4, col = lane & 15;
    const int rl = lane >> 3;
    const int cs = (lane & 7) ^ rl;

    { float4 v = ((const float4*)(eef + (size_t)k * NC))[t]; *(float4*)(eef_lds + t * 4) = v; }
    if (t < 128) { tv1[t] = 1e30f; tv2[t] = 1e30f; ti1[t] = 0; }

    // ---- A fragments: full K=256 in registers, split f16 hi/lo ----
    half8 Ah[2][8], Al[2][8];
    #pragma unroll
    for (int mi = 0; mi < 2; ++mi) {
        const float* xrow = x + ((size_t)(b0 + w * 32 + mi * 16 + col) * KC + k) * DC + quad * 8;
        #pragma unroll
        for (int ks = 0; ks < 8; ++ks) {
            float4 u0 = *(const float4*)(xrow + ks * 32);
            float4 u1 = *(const float4*)(xrow + ks * 32 + 4);
            float f[8] = {u0.x, u0.y, u0.z, u0.w, u1.x, u1.y, u1.z, u1.w};
            half8 h, l;
            #pragma unroll
            for (int j = 0; j < 8; ++j) {
                h[j] = (_Float16)f[j];
                l[j] = (_Float16)(f[j] - (float)h[j]);
            }
            Ah[mi][ks] = h; Al[mi][ks] = l;
        }
    }

    const char* EcatK = (const char*)(Ecat + (size_t)k * NC * 512);
    #define ISSUE_B(buf, n0b, dcb)                                                          \
        {                                                                                   \
            _Pragma("unroll")                                                               \
            for (int j = 0; j < 8; ++j) {                                                   \
                int li = w * 8 + j; int tile = li >> 4, grp = li & 15;                      \
                const char* src = EcatK + (size_t)((n0b) + grp * 8 + rl) * 1024             \
                                + tile * 512 + (dcb) * 2 + cs * 16;                         \
                char* dst = (tile ? Bl[buf] : Bh[buf]) + grp * 1024 + lane * 16;            \
                async_load16(src, dst);                                                     \
            }                                                                               \
        }

    ISSUE_B(0, 0, 0);

    for (int nt = 0; nt < 8; ++nt) {
        const int n0 = nt * 128;
        floatx4 acc[2][8] = {};
        #pragma unroll
        for (int dcs = 0; dcs < 4; ++dcs) {
            const int step = nt * 4 + dcs;
            __syncthreads();                       // drains loads for buf[cur]
            if (step < 31) {
                const int ns = step + 1;
                ISSUE_B(ns & 1, (ns >> 2) * 128, (ns & 3) * 64);
            }
            const int cur = step & 1;
            #pragma unroll
            for (int kk = 0; kk < 2; ++kk) {
                const int cb = kk * 4 + quad;
                const int ks = dcs * 2 + kk;
                #pragma unroll
                for (int ni = 0; ni < 8; ++ni) {
                    half8 bh = ldsr(Bh[cur], ni * 16 + col, cb);
                    acc[0][ni] = __builtin_amdgcn_mfma_f32_16x16x32_f16(Ah[0][ks], bh, acc[0][ni], 0, 0, 0);
                    acc[1][ni] = __builtin_amdgcn_mfma_f32_16x16x32_f16(Ah[1][ks], bh, acc[1][ni], 0, 0, 0);
                    acc[0][ni] = __builtin_amdgcn_mfma_f32_16x16x32_f16(Al[0][ks], bh, acc[0][ni], 0, 0, 0);
                    acc[1][ni] = __builtin_amdgcn_mfma_f32_16x16x32_f16(Al[1][ks], bh, acc[1][ni], 0, 0, 0);
                    half8 bl = ldsr(Bl[cur], ni * 16 + col, cb);
                    acc[0][ni] = __builtin_amdgcn_mfma_f32_16x16x32_f16(Ah[0][ks], bl, acc[0][ni], 0, 0, 0);
                    acc[1][ni] = __builtin_amdgcn_mfma_f32_16x16x32_f16(Ah[1][ks], bl, acc[1][ni], 0, 0, 0);
                }
            }
        }
        // ---- per-nt epilogue: plain f32 top-2 + argmin index.
        // Exact/near ties (gap < TAU) are flagged and re-resolved in fp64 by
        // refine_kernel, so strict-< float tracking needs no tie-break keys. ----
        float ev[8];
        #pragma unroll
        for (int ni = 0; ni < 8; ++ni) ev[ni] = eef_lds[n0 + ni * 16 + col];
        #pragma unroll
        for (int mi = 0; mi < 2; ++mi) {
            #pragma unroll
            for (int reg = 0; reg < 4; ++reg) {
                float v1 = 1e30f, v2 = 1e30f; int i1 = 0;
                #pragma unroll
                for (int ni = 0; ni < 8; ++ni) {
                    float val = fmaf(-2.0f, acc[mi][ni][reg], ev[ni]);
                    int n = n0 + ni * 16 + col;
                    bool lt1 = val < v1;
                    bool lt2 = val < v2;
                    float nv2 = lt1 ? v1 : (lt2 ? val : v2);
                    v1 = lt1 ? val : v1;
                    i1 = lt1 ? n : i1;
                    v2 = nv2;
                }
                #pragma unroll
                for (int off = 1; off < 16; off <<= 1) {
                    float o1 = __shfl_xor(v1, off, 16);
                    float o2 = __shfl_xor(v2, off, 16);
                    int   oi = __shfl_xor(i1, off, 16);
                    bool sw = o1 < v1;
                    float hi = sw ? v1 : o1;          // max(v1, o1)
                    v1 = sw ? o1 : v1;
                    i1 = sw ? oi : i1;
                    v2 = fminf(fminf(v2, o2), hi);
                }
                if (col == 0) {                       // same lane owns this row every nt
                    int row = w * 32 + mi * 16 + quad * 4 + reg;
                    float t1 = tv1[row], t2 = tv2[row];
                    bool sw = v1 < t1;
                    float hi = sw ? t1 : v1;          // max(t1, v1)
                    tv2[row] = fminf(fminf(t2, v2), hi);
                    tv1[row] = sw ? v1 : t1;
                    if (sw) ti1[row] = i1;
                }
            }
        }
    }

    // ---- final: resolve idx / flag near-ties ----
    __syncthreads();
    if (t < 128) {
        float v1 = tv1[t], v2 = tv2[t];
        int rid = (b0 + t) * KC + k;
        if (v2 - v1 < TAU) {
            int pos = atomicAdd(flag_cnt, 1);
            flag_list[pos] = rid;
            idx_lds[t] = -1;
        } else {
            int n = ti1[t];
            idx_lds[t] = n;
            out_idx[rid] = (float)n;
        }
    }
    __syncthreads();

    // ---- fused gather (out_q) + exact fp64 loss for resolved rows ----
    double s = 0.0;
    #pragma unroll
    for (int rr = 0; rr < 8; ++rr) {
        int r = rr * 16 + (t >> 4);
        int c = t & 15;
        int n = idx_lds[r];
        if (n >= 0) {
            const float4* xp = (const float4*)(x + ((size_t)(b0 + r) * KC + k) * DC);
            const float4* ep = (const float4*)(entries + ((size_t)k * NC + n) * DC);
            float4* op = (float4*)(out_q + ((size_t)(b0 + r) * KC + k) * DC);
            #pragma unroll
            for (int j = 0; j < 4; ++j) {
                int ci = j * 16 + c;
                float4 xv = xp[ci], evv = ep[ci];
                op[ci] = evv;
                double d0 = (double)xv.x - evv.x, d1 = (double)xv.y - evv.y;
                double d2 = (double)xv.z - evv.z, d3 = (double)xv.w - evv.w;
                s += d0 * d0 + d1 * d1 + d2 * d2 + d3 * d3;
            }
        }
    }
    red[t] = s;
    __syncthreads();
    for (int off2 = 128; off2 > 0; off2 >>= 1) {
        if (t < off2) red[t] += red[t + off2];
        __syncthreads();
    }
    if (t == 0) partial[blockIdx.x] = red[0];
    #undef ISSUE_B
}

// ---------------------------------------------------------------------------
// REF: exact fp64 re-resolution of flagged rows; writes idx, out_q, loss.
// Wave-cooperative: each wave owns 256 entries; per entry, lane holds 4 dims
// (coalesced float4 loads) and the wave shfl-reduces the fp64 distance.
// ---------------------------------------------------------------------------
__global__ __launch_bounds__(256) void refine_kernel(const float* __restrict__ x,
                                                     const float* __restrict__ entries,
                                                     const int* __restrict__ flag_list,
                                                     const int* __restrict__ flag_cnt,
                                                     float* __restrict__ out_idx,
                                                     float* __restrict__ out_q,
                                                     double* __restrict__ refAcc) {
    __shared__ double wbest[4];
    __shared__ int    wbn[4];
    __shared__ int    win;
    const int t = threadIdx.x;
    const int wave = t >> 6, lane = t & 63;
    int cnt = *flag_cnt;
    for (int i = blockIdx.x; i < cnt; i += gridDim.x) {
        int rid = flag_list[i];
        int k = rid & 7;
        float4 xv = ((const float4*)(x + (size_t)rid * DC))[lane];
        double x0 = xv.x, x1 = xv.y, x2 = xv.z, x3 = xv.w;
        double best = 1.0e300; int bn = 0;
        for (int e = 0; e < 256; ++e) {
            int n = wave * 256 + e;
            float4 ev = ((const float4*)(entries + ((size_t)k * NC + n) * DC))[lane];
            double d0 = x0 - (double)ev.x, d1 = x1 - (double)ev.y;
            double d2 = x2 - (double)ev.z, d3 = x3 - (double)ev.w;
            double s = d0 * d0 + d1 * d1 + d2 * d2 + d3 * d3;
            #pragma unroll
            for (int off = 32; off > 0; off >>= 1) s += __shfl_down(s, off, 64);
            if (lane == 0 && s < best) { best = s; bn = n; }
        }
        if (lane == 0) { wbest[wave] = best; wbn[wave] = bn; }
        __syncthreads();
        if (t == 0) {
            double b = wbest[0]; int n = wbn[0];
            for (int wv = 1; wv < 4; ++wv) {
                if (wbest[wv] < b || (wbest[wv] == b && wbn[wv] < n)) {
                    b = wbest[wv]; n = wbn[wv];
                }
            }
            out_idx[rid] = (float)n;
            win = n;
            atomicAdd(refAcc, b);
        }
        __syncthreads();
        out_q[(size_t)rid * DC + t] = entries[((size_t)k * NC + win) * DC + t];
        __syncthreads();
    }
}

__global__ __launch_bounds__(256) void finalize_kernel(const double* __restrict__ partial,
                                                       const double* __restrict__ refAcc,
                                                       float* __restrict__ out) {
    __shared__ double red[256];
    const int t = threadIdx.x;
    double s = 0.0;
    for (int i = t; i < 512; i += 256) s += partial[i];
    red[t] = s;
    __syncthreads();
    for (int off = 128; off > 0; off >>= 1) {
        if (t < off) red[t] += red[t + off];
        __syncthreads();
    }
    if (t == 0) {
        double L = (red[0] + *refAcc) * (1.0 / 65536.0);
        out[(size_t)BATCH * KC * DC + BATCH * KC + 0] = (float)L;
        out[(size_t)BATCH * KC * DC + BATCH * KC + 1] = (float)(0.25 * L);
    }
}

extern "C" void kernel_launch(void* const* d_in, const int* in_sizes, int n_in,
                              void* d_out, int out_size, void* d_ws, size_t ws_size,
                              hipStream_t stream) {
    const float* x       = (const float*)d_in[0];   // [8192, 8, 256]
    const float* entries = (const float*)d_in[1];   // [8, 1024, 256]
    float* out = (float*)d_out;

    char* ws = (char*)d_ws;
    int*      flag_cnt  = (int*)ws;                         // +0
    double*   refAcc    = (double*)(ws + 8);                // +8
    double*   partial   = (double*)(ws + 4096);             // 512 doubles
    float*    eef       = (float*)(ws + 65536);             // 32 KB
    int*      flag_list = (int*)(ws + 131072);              // 256 KB
    _Float16* Ecat      = (_Float16*)(ws + 1048576);        // 8 MB

    float* out_q   = out;                                   // 16,777,216 floats
    float* out_idx = out + (size_t)BATCH * KC * DC;         // 65,536 floats

    hipMemsetAsync(ws, 0, 16, stream);
    prep_e_kernel<<<KC * NC / 4, 256, 0, stream>>>(entries, Ecat, eef);
    vq_gemm<<<512, 256, 0, stream>>>(x, entries, Ecat, eef, out_idx, out_q,
                                     partial, flag_list, flag_cnt);
    refine_kernel<<<128, 256, 0, stream>>>(x, entries, flag_list, flag_cnt,
                                           out_idx, out_q, refAcc);
    finalize_kernel<<<1, 256, 0, stream>>>(partial, refAcc, out);
}

// Round 2
// 285.605 us; speedup vs baseline: 1.3049x; 1.3049x over previous
//
#include <hip/hip_runtime.h>
#include <cstdint>
#include <cstddef>

#define BATCH 8192
#define KC 8
#define NC 1024
#define DC 256
#define TAU 1e-3f

typedef __attribute__((ext_vector_type(8))) _Float16 half8;
typedef __attribute__((ext_vector_type(4))) _Float16 half4;
typedef __attribute__((ext_vector_type(4))) float floatx4;

__device__ __forceinline__ void async_load16(const void* g, void* l) {
    __builtin_amdgcn_global_load_lds((const __attribute__((address_space(1))) uint32_t*)g,
                                     (__attribute__((address_space(3))) uint32_t*)l, 16, 0, 0);
}

// ---------------------------------------------------------------------------
// P: entries -> Ecat f16 [row][512] = [eh(256) | el(256)]; eef = fp32(|e|^2 via fp64)
// ---------------------------------------------------------------------------
__global__ __launch_bounds__(256) void prep_e_kernel(const float* __restrict__ entries,
                                                     _Float16* __restrict__ Ecat,
                                                     float* __restrict__ eef) {
    int wave = threadIdx.x >> 6, lane = threadIdx.x & 63;
    int row = blockIdx.x * 4 + wave;            // [0, 8192) = k*NC + n
    float4 v = ((const float4*)(entries + (size_t)row * DC))[lane];
    half4 h, l;
    h.x = (_Float16)v.x; h.y = (_Float16)v.y; h.z = (_Float16)v.z; h.w = (_Float16)v.w;
    l.x = (_Float16)(v.x - (float)h.x); l.y = (_Float16)(v.y - (float)h.y);
    l.z = (_Float16)(v.z - (float)h.z); l.w = (_Float16)(v.w - (float)h.w);
    _Float16* rp = Ecat + (size_t)row * 512;
    *(half4*)(rp + lane * 4)       = h;
    *(half4*)(rp + 256 + lane * 4) = l;
    double s = (double)v.x * v.x + (double)v.y * v.y + (double)v.z * v.z + (double)v.w * v.w;
    #pragma unroll
    for (int off = 32; off > 0; off >>= 1) s += __shfl_down(s, off, 64);
    if (lane == 0) eef[row] = (float)s;
}

// ---------------------------------------------------------------------------
// GEMM: grid 512 (k = blk&7 -> XCD-pinned, bt = blk>>3). 4 waves x 32 rows.
// A full-K in registers (split f16 hi/lo). B streamed via global_load_lds into
// a ring of FOUR 16KB stage buffers (32-dim slices, hi+lo), prefetch depth 3,
// counted s_waitcnt vmcnt(8) + raw s_barrier per stage (never drain in loop),
// s_setprio(1) around the MFMA cluster.  (T3+T4+T5 from the 8-phase template.)
// Per-stage LDS swizzle: row r (64B = 4 chunks of 16B), chunk c stored at line
// r>>1, slot ((r&1)*4+c)^((r>>1)&7) -> 8 lanes per bank-quad on ds_read_b128
// (same density as the previously-measured 0-conflict layout).  Realized via
// pre-swizzled global source addresses (global_load_lds writes linearly).
// ---------------------------------------------------------------------------
__global__ __launch_bounds__(256, 2) void vq_gemm(const float* __restrict__ x,
                                                  const float* __restrict__ entries,
                                                  const _Float16* __restrict__ Ecat,
                                                  const float* __restrict__ eef,
                                                  float* __restrict__ out_idx,
                                                  float* __restrict__ out_q,
                                                  double* __restrict__ partial,
                                                  int* __restrict__ flag_list,
                                                  int* __restrict__ flag_cnt) {
    __shared__ alignas(16) char Bst[4][16384];   // stage = [hi 8KB | lo 8KB]
    __shared__ float eef_lds[NC];
    __shared__ float tv1[128];
    __shared__ float tv2[128];
    __shared__ int   ti1[128];
    __shared__ int   idx_lds[128];
    __shared__ double red[256];

    const int t = threadIdx.x;
    const int k  = blockIdx.x & 7;
    const int b0 = (blockIdx.x >> 3) * 128;
    const int w = t >> 6, lane = t & 63;
    const int quad = lane >> 4, col = lane & 15;

    // read-side swizzled offset (per-thread constant):
    const int slotr = (((col & 1) << 2) | quad) ^ (col >> 1);
    const int ldoff = (col >> 1) * 128 + slotr * 16;
    // write-side (source pre-swizzle) constants: lane -> (row-in-region, chunk)
    const int usrc = (lane & 7) ^ (lane >> 3);
    const int rloc = ((lane >> 3) << 1) | (usrc >> 2);
    const int csrc = usrc & 3;

    { float4 v = ((const float4*)(eef + (size_t)k * NC))[t]; *(float4*)(eef_lds + t * 4) = v; }
    if (t < 128) { tv1[t] = 1e30f; tv2[t] = 1e30f; ti1[t] = 0; }

    // ---- A fragments: full K=256 in registers, split f16 hi/lo ----
    half8 Ah[2][8], Al[2][8];
    #pragma unroll
    for (int mi = 0; mi < 2; ++mi) {
        const float* xrow = x + ((size_t)(b0 + w * 32 + mi * 16 + col) * KC + k) * DC + quad * 8;
        #pragma unroll
        for (int ks = 0; ks < 8; ++ks) {
            float4 u0 = *(const float4*)(xrow + ks * 32);
            float4 u1 = *(const float4*)(xrow + ks * 32 + 4);
            float f[8] = {u0.x, u0.y, u0.z, u0.w, u1.x, u1.y, u1.z, u1.w};
            half8 h, l;
            #pragma unroll
            for (int j = 0; j < 8; ++j) {
                h[j] = (_Float16)f[j];
                l[j] = (_Float16)(f[j] - (float)h[j]);
            }
            Ah[mi][ks] = h; Al[mi][ks] = l;
        }
    }

    const char* EcatK = (const char*)(Ecat + (size_t)k * NC * 512);

    // stage st (0..63): nt = st>>3, 32-dim slice d0 = (st&7)*32, buffer st&3.
    // 16 regions of 1KB (8 hi + 8 lo); 4 waves x 4 loads -> 4 vmcnt ticks/wave/stage.
    #define ISSUE_B(st_)                                                                 \
        {                                                                                \
            const int nti_ = (st_) >> 3;                                                 \
            const int d0i_ = ((st_) & 7) * 32;                                           \
            char* bb_ = Bst[(st_) & 3];                                                  \
            _Pragma("unroll")                                                            \
            for (int j = 0; j < 4; ++j) {                                                \
                int li_ = (w << 2) | j; int tile_ = li_ >> 3, grp_ = li_ & 7;            \
                const char* src_ = EcatK                                                 \
                    + (size_t)(nti_ * 128 + grp_ * 16 + rloc) * 1024                     \
                    + tile_ * 512 + d0i_ * 2 + csrc * 16;                                \
                async_load16(src_, bb_ + tile_ * 8192 + grp_ * 1024 + lane * 16);        \
            }                                                                            \
        }

    // One pipeline stage: counted wait (own oldest 4 loads), barrier (others'),
    // issue stage+3, then 16 ds_read_b128 + 48 MFMA.
    #define STAGE(nt_, ds0_, WN_, DOISS_)                                                \
        {                                                                                \
            asm volatile("s_waitcnt vmcnt(" #WN_ ")" ::: "memory");                      \
            __builtin_amdgcn_s_barrier();                                                \
            __builtin_amdgcn_sched_barrier(0);                                           \
            if (DOISS_) { ISSUE_B((nt_) * 8 + (ds0_) + 3); }                             \
            const char* Bs_ = Bst[(ds0_) & 3];  /* (nt*8+ds0)&3 == ds0&3 */              \
            __builtin_amdgcn_s_setprio(1);                                               \
            _Pragma("unroll")                                                            \
            for (int ni = 0; ni < 8; ++ni) {                                             \
                half8 bh = *(const half8*)(Bs_ + ni * 1024 + ldoff);                     \
                acc[0][ni] = __builtin_amdgcn_mfma_f32_16x16x32_f16(Ah[0][ds0_], bh, acc[0][ni], 0, 0, 0); \
                acc[1][ni] = __builtin_amdgcn_mfma_f32_16x16x32_f16(Ah[1][ds0_], bh, acc[1][ni], 0, 0, 0); \
                acc[0][ni] = __builtin_amdgcn_mfma_f32_16x16x32_f16(Al[0][ds0_], bh, acc[0][ni], 0, 0, 0); \
                acc[1][ni] = __builtin_amdgcn_mfma_f32_16x16x32_f16(Al[1][ds0_], bh, acc[1][ni], 0, 0, 0); \
                half8 bl = *(const half8*)(Bs_ + 8192 + ni * 1024 + ldoff);              \
                acc[0][ni] = __builtin_amdgcn_mfma_f32_16x16x32_f16(Ah[0][ds0_], bl, acc[0][ni], 0, 0, 0); \
                acc[1][ni] = __builtin_amdgcn_mfma_f32_16x16x32_f16(Ah[1][ds0_], bl, acc[1][ni], 0, 0, 0); \
            }                                                                            \
            __builtin_amdgcn_s_setprio(0);                                               \
        }

    __syncthreads();            // eef/tv init visible; drains prologue vmem
    ISSUE_B(0); ISSUE_B(1); ISSUE_B(2);

    for (int nt = 0; nt < 8; ++nt) {
        const int n0 = nt * 128;
        floatx4 acc[2][8] = {};
        if (nt < 7) {
            #pragma unroll
            for (int ds0 = 0; ds0 < 8; ++ds0) STAGE(nt, ds0, 8, 1)
        } else {
            STAGE(7, 0, 8, 1) STAGE(7, 1, 8, 1) STAGE(7, 2, 8, 1)
            STAGE(7, 3, 8, 1) STAGE(7, 4, 8, 1)
            STAGE(7, 5, 8, 0) STAGE(7, 6, 4, 0) STAGE(7, 7, 0, 0)
        }
        // ---- per-nt epilogue: plain f32 top-2 + argmin (ties -> refine) ----
        float ev[8];
        #pragma unroll
        for (int ni = 0; ni < 8; ++ni) ev[ni] = eef_lds[n0 + ni * 16 + col];
        #pragma unroll
        for (int mi = 0; mi < 2; ++mi) {
            #pragma unroll
            for (int reg = 0; reg < 4; ++reg) {
                float v1 = 1e30f, v2 = 1e30f; int i1 = 0;
                #pragma unroll
                for (int ni = 0; ni < 8; ++ni) {
                    float val = fmaf(-2.0f, acc[mi][ni][reg], ev[ni]);
                    int n = n0 + ni * 16 + col;
                    bool lt1 = val < v1;
                    bool lt2 = val < v2;
                    float nv2 = lt1 ? v1 : (lt2 ? val : v2);
                    v1 = lt1 ? val : v1;
                    i1 = lt1 ? n : i1;
                    v2 = nv2;
                }
                #pragma unroll
                for (int off = 1; off < 16; off <<= 1) {
                    float o1 = __shfl_xor(v1, off, 16);
                    float o2 = __shfl_xor(v2, off, 16);
                    int   oi = __shfl_xor(i1, off, 16);
                    bool sw = o1 < v1;
                    float hi = sw ? v1 : o1;          // max(v1, o1)
                    v1 = sw ? o1 : v1;
                    i1 = sw ? oi : i1;
                    v2 = fminf(fminf(v2, o2), hi);
                }
                if (col == 0) {                       // same lane owns this row every nt
                    int row = w * 32 + mi * 16 + quad * 4 + reg;
                    float t1 = tv1[row], t2 = tv2[row];
                    bool sw = v1 < t1;
                    float hi = sw ? t1 : v1;          // max(t1, v1)
                    tv2[row] = fminf(fminf(t2, v2), hi);
                    tv1[row] = sw ? v1 : t1;
                    if (sw) ti1[row] = i1;
                }
            }
        }
    }

    // ---- final: resolve idx / flag near-ties ----
    __syncthreads();
    if (t < 128) {
        float v1 = tv1[t], v2 = tv2[t];
        int rid = (b0 + t) * KC + k;
        if (v2 - v1 < TAU) {
            int pos = atomicAdd(flag_cnt, 1);
            flag_list[pos] = rid;
            idx_lds[t] = -1;
        } else {
            int n = ti1[t];
            idx_lds[t] = n;
            out_idx[rid] = (float)n;
        }
    }
    __syncthreads();

    // ---- fused gather (out_q) + exact fp64 loss for resolved rows ----
    double s = 0.0;
    #pragma unroll
    for (int rr = 0; rr < 8; ++rr) {
        int r = rr * 16 + (t >> 4);
        int c = t & 15;
        int n = idx_lds[r];
        if (n >= 0) {
            const float4* xp = (const float4*)(x + ((size_t)(b0 + r) * KC + k) * DC);
            const float4* ep = (const float4*)(entries + ((size_t)k * NC + n) * DC);
            float4* op = (float4*)(out_q + ((size_t)(b0 + r) * KC + k) * DC);
            #pragma unroll
            for (int j = 0; j < 4; ++j) {
                int ci = j * 16 + c;
                float4 xv = xp[ci], evv = ep[ci];
                op[ci] = evv;
                double d0 = (double)xv.x - evv.x, d1 = (double)xv.y - evv.y;
                double d2 = (double)xv.z - evv.z, d3 = (double)xv.w - evv.w;
                s += d0 * d0 + d1 * d1 + d2 * d2 + d3 * d3;
            }
        }
    }
    red[t] = s;
    __syncthreads();
    for (int off2 = 128; off2 > 0; off2 >>= 1) {
        if (t < off2) red[t] += red[t + off2];
        __syncthreads();
    }
    if (t == 0) partial[blockIdx.x] = red[0];
    #undef STAGE
    #undef ISSUE_B
}

// ---------------------------------------------------------------------------
// REF: exact fp64 re-resolution of flagged rows (block per row, thread per 4
// entries, float4 loads + 4 independent fp64 accumulators).
// ---------------------------------------------------------------------------
__global__ __launch_bounds__(256) void refine_kernel(const float* __restrict__ x,
                                                     const float* __restrict__ entries,
                                                     const int* __restrict__ flag_list,
                                                     const int* __restrict__ flag_cnt,
                                                     float* __restrict__ out_idx,
                                                     float* __restrict__ out_q,
                                                     double* __restrict__ refAcc) {
    __shared__ float xs[DC];
    __shared__ double bd[256];
    __shared__ int    bi[256];
    __shared__ int    win;
    const int t = threadIdx.x;
    int cnt = *flag_cnt;
    for (int i = blockIdx.x; i < cnt; i += gridDim.x) {
        int rid = flag_list[i];
        int k = rid & 7;
        __syncthreads();
        xs[t] = x[(size_t)rid * DC + t];
        __syncthreads();
        double best = 1.0e300; int bn = 0;
        const float4* xp = (const float4*)xs;
        for (int e = 0; e < 4; ++e) {
            int n = t * 4 + e;
            const float4* ep = (const float4*)(entries + ((size_t)k * NC + n) * DC);
            double s0 = 0.0, s1 = 0.0, s2 = 0.0, s3 = 0.0;
            #pragma unroll 8
            for (int d4 = 0; d4 < 64; ++d4) {
                float4 ev = ep[d4]; float4 xv = xp[d4];
                double d0 = (double)xv.x - ev.x, d1 = (double)xv.y - ev.y;
                double d2 = (double)xv.z - ev.z, d3 = (double)xv.w - ev.w;
                s0 += d0 * d0; s1 += d1 * d1; s2 += d2 * d2; s3 += d3 * d3;
            }
            double s = (s0 + s1) + (s2 + s3);
            if (s < best) { best = s; bn = n; }
        }
        bd[t] = best; bi[t] = bn;
        __syncthreads();
        for (int s2 = 128; s2 > 0; s2 >>= 1) {
            if (t < s2) {
                if (bd[t + s2] < bd[t] || (bd[t + s2] == bd[t] && bi[t + s2] < bi[t])) {
                    bd[t] = bd[t + s2]; bi[t] = bi[t + s2];
                }
            }
            __syncthreads();
        }
        if (t == 0) {
            out_idx[rid] = (float)bi[0];
            win = bi[0];
            atomicAdd(refAcc, bd[0]);
        }
        __syncthreads();
        out_q[(size_t)rid * DC + t] = entries[((size_t)k * NC + win) * DC + t];
        __syncthreads();
    }
}

__global__ __launch_bounds__(256) void finalize_kernel(const double* __restrict__ partial,
                                                       const double* __restrict__ refAcc,
                                                       float* __restrict__ out) {
    __shared__ double red[256];
    const int t = threadIdx.x;
    double s = 0.0;
    for (int i = t; i < 512; i += 256) s += partial[i];
    red[t] = s;
    __syncthreads();
    for (int off = 128; off > 0; off >>= 1) {
        if (t < off) red[t] += red[t + off];
        __syncthreads();
    }
    if (t == 0) {
        double L = (red[0] + *refAcc) * (1.0 / 65536.0);
        out[(size_t)BATCH * KC * DC + BATCH * KC + 0] = (float)L;
        out[(size_t)BATCH * KC * DC + BATCH * KC + 1] = (float)(0.25 * L);
    }
}

extern "C" void kernel_launch(void* const* d_in, const int* in_sizes, int n_in,
                              void* d_out, int out_size, void* d_ws, size_t ws_size,
                              hipStream_t stream) {
    const float* x       = (const float*)d_in[0];   // [8192, 8, 256]
    const float* entries = (const float*)d_in[1];   // [8, 1024, 256]
    float* out = (float*)d_out;

    char* ws = (char*)d_ws;
    int*      flag_cnt  = (int*)ws;                         // +0
    double*   refAcc    = (double*)(ws + 8);                // +8
    double*   partial   = (double*)(ws + 4096);             // 512 doubles
    float*    eef       = (float*)(ws + 65536);             // 32 KB
    int*      flag_list = (int*)(ws + 131072);              // 256 KB
    _Float16* Ecat      = (_Float16*)(ws + 1048576);        // 8 MB

    float* out_q   = out;                                   // 16,777,216 floats
    float* out_idx = out + (size_t)BATCH * KC * DC;         // 65,536 floats

    hipMemsetAsync(ws, 0, 16, stream);
    prep_e_kernel<<<KC * NC / 4, 256, 0, stream>>>(entries, Ecat, eef);
    vq_gemm<<<512, 256, 0, stream>>>(x, entries, Ecat, eef, out_idx, out_q,
                                     partial, flag_list, flag_cnt);
    refine_kernel<<<256, 256, 0, stream>>>(x, entries, flag_list, flag_cnt,
                                           out_idx, out_q, refAcc);
    finalize_kernel<<<1, 256, 0, stream>>>(partial, refAcc, out);
}